// Round 7
// baseline (440.948 us; speedup 1.0000x reference)
//
#include <hip/hip_runtime.h>
#include <stdint.h>

#define NN 100000
#define NE 1600000
#define NMASKW 400000  // (NN*128)/32 mask words per layer

typedef float f4 __attribute__((ext_vector_type(4)));
typedef float f2 __attribute__((ext_vector_type(2)));
typedef unsigned short us4 __attribute__((ext_vector_type(4)));
typedef short s16x8 __attribute__((ext_vector_type(8)));

__device__ inline float bf2f(unsigned short u) {
  return __uint_as_float(((uint32_t)u) << 16);
}
__device__ inline unsigned short f2bf(float f) {  // round-to-nearest-even
  uint32_t u = __float_as_uint(f);
  return (unsigned short)((u + 0x7fffu + ((u >> 16) & 1u)) >> 16);
}
__device__ inline float lo16(uint32_t q) { return __uint_as_float(q << 16); }
__device__ inline float hi16(uint32_t q) { return __uint_as_float(q & 0xffff0000u); }

// Threefry-2x32, 20 rounds (Random123 / JAX exact).
__host__ __device__ inline void threefry2x32(uint32_t k0, uint32_t k1,
                                             uint32_t x0, uint32_t x1,
                                             uint32_t* y0, uint32_t* y1) {
  uint32_t ks[3] = {k0, k1, k0 ^ k1 ^ 0x1BD11BDAu};
  x0 += ks[0]; x1 += ks[1];
  const uint32_t R[2][4] = {{13u, 15u, 26u, 6u}, {17u, 29u, 16u, 24u}};
#pragma unroll
  for (int i = 0; i < 5; ++i) {
#pragma unroll
    for (int j = 0; j < 4; ++j) {
      uint32_t r = R[i & 1][j];
      x0 += x1;
      x1 = (x1 << r) | (x1 >> (32u - r));
      x1 ^= x0;
    }
    x0 += ks[(i + 1) % 3];
    x1 += ks[(i + 2) % 3] + (uint32_t)(i + 1);
  }
  *y0 = x0; *y1 = x1;
}

__device__ inline uint32_t tf_bits32(uint32_t k0, uint32_t k1, uint32_t idx) {
  uint32_t a, b;
  threefry2x32(k0, k1, 0u, idx, &a, &b);
  return a ^ b;
}

// Dropout mask words: bit j of word t = MSB of bits(32t+j) (1 = drop).
__global__ __launch_bounds__(256) void k_mask(uint32_t* __restrict__ m1,
                                              uint32_t* __restrict__ m2,
                                              uint32_t k10, uint32_t k11,
                                              uint32_t k20, uint32_t k21) {
  int t = blockIdx.x * 256 + threadIdx.x;
  if (t >= NMASKW) return;
  uint32_t base = (uint32_t)t * 32u;
  uint32_t w1 = 0, w2 = 0;
#pragma unroll 4
  for (int j = 0; j < 32; ++j) {
    w1 |= (tf_bits32(k10, k11, base + j) >> 31) << j;
    w2 |= (tf_bits32(k20, k21, base + j) >> 31) << j;
  }
  m1[t] = w1;
  m2[t] = w2;
}

__global__ void k_init(uint32_t* cnt) {
  int i = blockIdx.x * 256 + threadIdx.x;
  if (i < NN) cnt[i] = 0u;
}

__global__ void k_hist(const int* __restrict__ ei, uint32_t* __restrict__ cnt,
                       int* __restrict__ slot) {
  int e = blockIdx.x * 256 + threadIdx.x;
  if (e < NE) {
    int d = ei[NE + e];
    slot[e] = (int)atomicAdd(&cnt[d], 1u);
  }
}

__global__ void k_dinv(const uint32_t* __restrict__ cnt, float* __restrict__ dinv) {
  int i = blockIdx.x * 256 + threadIdx.x;
  if (i < NN) dinv[i] = 1.0f / sqrtf((float)(cnt[i] + 1u));
}

__global__ __launch_bounds__(256) void k_scan1(const uint32_t* __restrict__ cnt,
                                               uint32_t* __restrict__ rp,
                                               uint32_t* __restrict__ bsum) {
  __shared__ uint32_t sh[256];
  int t = threadIdx.x;
  int base = blockIdx.x * 1024 + t * 4;
  uint32_t v[4];
  uint32_t s = 0;
#pragma unroll
  for (int i = 0; i < 4; ++i) {
    int idx = base + i;
    v[i] = (idx < NN) ? cnt[idx] : 0u;
    s += v[i];
  }
  sh[t] = s;
  __syncthreads();
  for (int off = 1; off < 256; off <<= 1) {
    uint32_t x = sh[t];
    if (t >= off) x += sh[t - off];
    __syncthreads();
    sh[t] = x;
    __syncthreads();
  }
  uint32_t run = (t > 0) ? sh[t - 1] : 0u;
  if (t == 255) bsum[blockIdx.x] = sh[255];
#pragma unroll
  for (int i = 0; i < 4; ++i) {
    int idx = base + i;
    if (idx < NN) rp[idx] = run;
    run += v[i];
  }
}

__global__ void k_scan2(uint32_t* bsum, int nb) {
  if (threadIdx.x == 0 && blockIdx.x == 0) {
    uint32_t s = 0;
    for (int i = 0; i < nb; ++i) { uint32_t x = bsum[i]; bsum[i] = s; s += x; }
  }
}

__global__ void k_scan3(uint32_t* rp, const uint32_t* __restrict__ bsum) {
  int i = blockIdx.x * 256 + threadIdx.x;
  if (i < NN) rp[i] += bsum[i >> 10];
  if (i == 0) rp[NN] = (uint32_t)NE;
}

// Edge record (src, w=dinv[s]*dinv[d]) at CSR position; no atomics.
__global__ void k_scatter(const int* __restrict__ ei,
                          const uint32_t* __restrict__ rp,
                          const int* __restrict__ slot,
                          const float* __restrict__ dinv,
                          uint2* __restrict__ e2) {
  int e = blockIdx.x * 256 + threadIdx.x;
  if (e < NE) {
    int s = ei[e];
    int d = ei[NE + e];
    float w = dinv[s] * dinv[d];
    uint32_t pos = rp[d] + (uint32_t)slot[e];
    uint2 rec;
    rec.x = (uint32_t)s;
    rec.y = __float_as_uint(w);
    e2[pos] = rec;
  }
}

// W [128][dout] f32 -> packed MFMA B-frag layout, hi/lo:
// out[((ct*4+kk)*64 + lane)*8 + j] = W[kk*32 + (lane>>4)*8 + j][ct*16 + (lane&15)]
__global__ void k_wsplit(const float* __restrict__ W, int dout,
                         unsigned short* __restrict__ H,
                         unsigned short* __restrict__ L) {
  int lane = threadIdx.x;  // 64
  int kk = blockIdx.x & 3;
  int ct = blockIdx.x >> 2;
  int kbase = kk * 32 + (lane >> 4) * 8;
  int col = ct * 16 + (lane & 15);
  us4 h0, h1, l0, l1;
#pragma unroll
  for (int j = 0; j < 4; ++j) {
    float v = W[(size_t)(kbase + j) * dout + col];
    h0[j] = f2bf(v);
    l0[j] = f2bf(v - bf2f(h0[j]));
    float v2 = W[(size_t)(kbase + 4 + j) * dout + col];
    h1[j] = f2bf(v2);
    l1[j] = f2bf(v2 - bf2f(h1[j]));
  }
  size_t o = ((size_t)blockIdx.x * 64 + lane) * 8;
  *(us4*)(H + o) = h0; *(us4*)(H + o + 4) = h1;
  *(us4*)(L + o) = l0; *(us4*)(L + o + 4) = l1;
}

// Layer-1 GEMM: A is f32 (x), split hi/lo in-register. C bf16.
__global__ __launch_bounds__(256) void k_gemm1(
    const float* __restrict__ A, const unsigned short* __restrict__ Wh,
    const unsigned short* __restrict__ Wl, unsigned short* __restrict__ C) {
  constexpr int NT = 8;  // DOUT=128
  const int w = threadIdx.x >> 6;
  const int lane = threadIdx.x & 63;
  const int row0 = blockIdx.x * 64 + w * 16;
  int ar = row0 + (lane & 15);
  if (ar >= NN) ar = NN - 1;
  const int aoff = (lane >> 4) * 8;
  s16x8 afh[4], afl[4];
#pragma unroll
  for (int kk = 0; kk < 4; ++kk) {
    f4 v0 = *(const f4*)(A + (size_t)ar * 128 + kk * 32 + aoff);
    f4 v1 = *(const f4*)(A + (size_t)ar * 128 + kk * 32 + aoff + 4);
#pragma unroll
    for (int j = 0; j < 4; ++j) {
      unsigned short h = f2bf(v0[j]);
      afh[kk][j] = (short)h;
      afl[kk][j] = (short)f2bf(v0[j] - bf2f(h));
      unsigned short h2 = f2bf(v1[j]);
      afh[kk][j + 4] = (short)h2;
      afl[kk][j + 4] = (short)f2bf(v1[j] - bf2f(h2));
    }
  }
  f4 acc[NT];
#pragma unroll
  for (int t = 0; t < NT; ++t) acc[t] = (f4){0.f, 0.f, 0.f, 0.f};
#pragma unroll
  for (int ct = 0; ct < NT; ++ct) {
#pragma unroll
    for (int kk = 0; kk < 4; ++kk) {
      size_t bo = ((size_t)(ct * 4 + kk) * 64 + lane) * 8;
      s16x8 bh = *(const s16x8*)(Wh + bo);
      s16x8 bl = *(const s16x8*)(Wl + bo);
      acc[ct] = __builtin_amdgcn_mfma_f32_16x16x32_bf16(afh[kk], bh, acc[ct], 0, 0, 0);
      acc[ct] = __builtin_amdgcn_mfma_f32_16x16x32_bf16(afh[kk], bl, acc[ct], 0, 0, 0);
      acc[ct] = __builtin_amdgcn_mfma_f32_16x16x32_bf16(afl[kk], bh, acc[ct], 0, 0, 0);
    }
  }
  const int rbase = row0 + (lane >> 4) * 4;
  const int cbase = lane & 15;
#pragma unroll
  for (int ct = 0; ct < NT; ++ct) {
#pragma unroll
    for (int r = 0; r < 4; ++r) {
      int gr = rbase + r;
      if (gr < NN) C[(size_t)gr * 128 + ct * 16 + cbase] = f2bf(acc[ct][r]);
    }
  }
}

// Layers 2/3 GEMM: A from hi/lo bf16 arrays (agg output).
template <int DOUT>
__global__ __launch_bounds__(256) void k_gemm_mfma(
    const unsigned short* __restrict__ Ah, const unsigned short* __restrict__ Al,
    const unsigned short* __restrict__ Wh, const unsigned short* __restrict__ Wl,
    unsigned short* __restrict__ C) {
  constexpr int NT = DOUT / 16;
  const int w = threadIdx.x >> 6;
  const int lane = threadIdx.x & 63;
  const int row0 = blockIdx.x * 64 + w * 16;
  int ar = row0 + (lane & 15);
  if (ar >= NN) ar = NN - 1;
  const int aoff = (lane >> 4) * 8;
  s16x8 afh[4], afl[4];
#pragma unroll
  for (int kk = 0; kk < 4; ++kk) {
    afh[kk] = *(const s16x8*)(Ah + (size_t)ar * 128 + kk * 32 + aoff);
    afl[kk] = *(const s16x8*)(Al + (size_t)ar * 128 + kk * 32 + aoff);
  }
  f4 acc[NT];
#pragma unroll
  for (int t = 0; t < NT; ++t) acc[t] = (f4){0.f, 0.f, 0.f, 0.f};
#pragma unroll
  for (int ct = 0; ct < NT; ++ct) {
#pragma unroll
    for (int kk = 0; kk < 4; ++kk) {
      size_t bo = ((size_t)(ct * 4 + kk) * 64 + lane) * 8;
      s16x8 bh = *(const s16x8*)(Wh + bo);
      s16x8 bl = *(const s16x8*)(Wl + bo);
      acc[ct] = __builtin_amdgcn_mfma_f32_16x16x32_bf16(afh[kk], bh, acc[ct], 0, 0, 0);
      acc[ct] = __builtin_amdgcn_mfma_f32_16x16x32_bf16(afh[kk], bl, acc[ct], 0, 0, 0);
      acc[ct] = __builtin_amdgcn_mfma_f32_16x16x32_bf16(afl[kk], bh, acc[ct], 0, 0, 0);
    }
  }
  const int rbase = row0 + (lane >> 4) * 4;
  const int cbase = lane & 15;
#pragma unroll
  for (int ct = 0; ct < NT; ++ct) {
#pragma unroll
    for (int r = 0; r < 4; ++r) {
      int gr = rbase + r;
      if (gr < NN) C[(size_t)gr * DOUT + ct * 16 + cbase] = f2bf(acc[ct][r]);
    }
  }
}

// Middle aggregation (D=128): edge records (src,w), unroll-8 gathers, mask-based
// dropout; writes hi/lo bf16 split for the next MFMA GEMM.
__global__ __launch_bounds__(256) void k_agg_mid(
    const unsigned short* __restrict__ hb, const uint32_t* __restrict__ rp,
    const uint2* __restrict__ e2, const float* __restrict__ dinv,
    const float* __restrict__ bias, const uint32_t* __restrict__ mask,
    unsigned short* __restrict__ oh, unsigned short* __restrict__ ol) {
  int wid = __builtin_amdgcn_readfirstlane(blockIdx.x * 4 + (threadIdx.x >> 6));
  if (wid >= NN) return;
  const int lane = threadIdx.x & 63;
  const uint32_t beg = rp[wid], end = rp[wid + 1];
  const float dv = dinv[wid];
  const float sn = dv * dv;
  const char* hbase = (const char*)hb;
  float a0 = 0.f, a1 = 0.f, c0 = 0.f, c1 = 0.f;
  uint32_t u = beg;
  for (; u + 8 <= end; u += 8) {
    uint2 r[8];
#pragma unroll
    for (int i = 0; i < 8; ++i) r[i] = e2[u + i];
    uint32_t q[8];
#pragma unroll
    for (int i = 0; i < 8; ++i)
      q[i] = ((const uint32_t*)(hbase + ((size_t)r[i].x << 8)))[lane];
#pragma unroll
    for (int i = 0; i < 8; ++i) {
      float w = __uint_as_float(r[i].y);
      if (i & 1) {
        c0 = fmaf(w, lo16(q[i]), c0);
        c1 = fmaf(w, hi16(q[i]), c1);
      } else {
        a0 = fmaf(w, lo16(q[i]), a0);
        a1 = fmaf(w, hi16(q[i]), a1);
      }
    }
  }
  for (; u < end; ++u) {
    uint2 r = e2[u];
    uint32_t q = ((const uint32_t*)(hbase + ((size_t)r.x << 8)))[lane];
    float w = __uint_as_float(r.y);
    a0 = fmaf(w, lo16(q), a0);
    a1 = fmaf(w, hi16(q), a1);
  }
  a0 += c0; a1 += c1;
  uint32_t qs = ((const uint32_t*)(hbase + ((size_t)(uint32_t)wid << 8)))[lane];
  f2 bv = *(const f2*)(bias + lane * 2);
  a0 = fmaf(sn, lo16(qs), a0) + bv[0];
  a1 = fmaf(sn, hi16(qs), a1) + bv[1];
  a0 = fmaxf(a0, 0.f);
  a1 = fmaxf(a1, 0.f);
  // dropout: word = mask[wid*4 + lane>>4], bits (lane&15)*2, +1. bit=1 -> drop.
  uint32_t mw = mask[(uint32_t)wid * 4u + (uint32_t)(lane >> 4)];
  uint32_t b = (uint32_t)((lane & 15) * 2);
  a0 = ((mw >> b) & 1u) ? 0.f : a0 * 2.f;
  a1 = ((mw >> (b + 1u)) & 1u) ? 0.f : a1 * 2.f;
  unsigned short h0 = f2bf(a0), h1 = f2bf(a1);
  unsigned short g0 = f2bf(a0 - bf2f(h0)), g1 = f2bf(a1 - bf2f(h1));
  ((uint32_t*)oh)[(size_t)wid * 64 + lane] = (uint32_t)h0 | ((uint32_t)h1 << 16);
  ((uint32_t*)ol)[(size_t)wid * 64 + lane] = (uint32_t)g0 | ((uint32_t)g1 << 16);
}

// Final aggregation (D=64): gather-sum + self-loop + bias, f32 out.
__global__ __launch_bounds__(256) void k_agg_final(
    const unsigned short* __restrict__ hb, const uint32_t* __restrict__ rp,
    const uint2* __restrict__ e2, const float* __restrict__ dinv,
    const float* __restrict__ bias, float* __restrict__ out) {
  int wid = __builtin_amdgcn_readfirstlane(blockIdx.x * 4 + (threadIdx.x >> 6));
  if (wid >= NN) return;
  const int lane = threadIdx.x & 63;
  const uint32_t beg = rp[wid], end = rp[wid + 1];
  const float dv = dinv[wid];
  const float sn = dv * dv;
  const char* hbase = (const char*)hb;
  float a0 = 0.f, c0 = 0.f, a2 = 0.f, c2 = 0.f;
  uint32_t u = beg;
  for (; u + 8 <= end; u += 8) {
    uint2 r[8];
#pragma unroll
    for (int i = 0; i < 8; ++i) r[i] = e2[u + i];
    uint32_t q[8];
#pragma unroll
    for (int i = 0; i < 8; ++i)
      q[i] = (uint32_t)((const unsigned short*)(hbase + ((size_t)r[i].x << 7)))[lane];
#pragma unroll
    for (int i = 0; i < 8; ++i) {
      float w = __uint_as_float(r[i].y);
      float hv = __uint_as_float(q[i] << 16);
      if ((i & 3) == 0) a0 = fmaf(w, hv, a0);
      else if ((i & 3) == 1) c0 = fmaf(w, hv, c0);
      else if ((i & 3) == 2) a2 = fmaf(w, hv, a2);
      else c2 = fmaf(w, hv, c2);
    }
  }
  for (; u < end; ++u) {
    uint2 r = e2[u];
    uint32_t q = (uint32_t)((const unsigned short*)(hbase + ((size_t)r.x << 7)))[lane];
    a0 = fmaf(__uint_as_float(r.y), __uint_as_float(q << 16), a0);
  }
  a0 += c0 + a2 + c2;
  uint32_t qs = (uint32_t)((const unsigned short*)(hbase + ((size_t)(uint32_t)wid << 7)))[lane];
  a0 = fmaf(sn, __uint_as_float(qs << 16), a0) + bias[lane];
  out[(size_t)wid * 64 + lane] = a0;
}

extern "C" void kernel_launch(void* const* d_in, const int* in_sizes, int n_in,
                              void* d_out, int out_size, void* d_ws, size_t ws_size,
                              hipStream_t stream) {
  (void)in_sizes; (void)n_in; (void)out_size; (void)ws_size;
  const float* x  = (const float*)d_in[0];
  const float* W1 = (const float*)d_in[1];
  const float* b1 = (const float*)d_in[2];
  const float* W2 = (const float*)d_in[3];
  const float* b2 = (const float*)d_in[4];
  const float* W3 = (const float*)d_in[5];
  const float* b3 = (const float*)d_in[6];
  const int* ei   = (const int*)d_in[7];
  float* out = (float*)d_out;

  char* p = (char*)d_ws;
  auto alloc = [&](size_t bytes) -> void* {
    void* r = (void*)p;
    p += (bytes + 255) & ~(size_t)255;
    return r;
  };
  uint32_t* cnt  = (uint32_t*)alloc((size_t)NN * 4);
  float*    dinv = (float*)alloc((size_t)NN * 4);
  uint32_t* rp   = (uint32_t*)alloc((size_t)(NN + 1) * 4);
  uint32_t* bsum = (uint32_t*)alloc(1024);
  int*      slot = (int*)alloc((size_t)NE * 4);
  uint2*    e2   = (uint2*)alloc((size_t)NE * 8);
  uint32_t* m1   = (uint32_t*)alloc((size_t)NMASKW * 4);
  uint32_t* m2   = (uint32_t*)alloc((size_t)NMASKW * 4);
  unsigned short* ah = (unsigned short*)alloc((size_t)NN * 128 * 2);
  unsigned short* al = (unsigned short*)alloc((size_t)NN * 128 * 2);
  unsigned short* hb = (unsigned short*)alloc((size_t)NN * 128 * 2);
  unsigned short* w1h = (unsigned short*)alloc(32 * 64 * 8 * 2);
  unsigned short* w1l = (unsigned short*)alloc(32 * 64 * 8 * 2);
  unsigned short* w2h = (unsigned short*)alloc(32 * 64 * 8 * 2);
  unsigned short* w2l = (unsigned short*)alloc(32 * 64 * 8 * 2);
  unsigned short* w3h = (unsigned short*)alloc(16 * 64 * 8 * 2);
  unsigned short* w3l = (unsigned short*)alloc(16 * 64 * 8 * 2);

  // JAX: kd1, kd2 = split(key(42)) — partitionable/fold-like split.
  uint32_t kd1a, kd1b, kd2a, kd2b;
  threefry2x32(0u, 42u, 0u, 0u, &kd1a, &kd1b);
  threefry2x32(0u, 42u, 0u, 1u, &kd2a, &kd2b);

  const int gbN = (NN + 255) / 256;
  const int gbE = (NE + 255) / 256;
  const int gbScan = (NN + 1023) / 1024;
  const int gbGemm = (NN + 63) / 64;
  const int gbAgg = (NN + 3) / 4;
  const int gbMask = (NMASKW + 255) / 256;

  k_init<<<gbN, 256, 0, stream>>>(cnt);
  k_hist<<<gbE, 256, 0, stream>>>(ei, cnt, slot);
  k_dinv<<<gbN, 256, 0, stream>>>(cnt, dinv);
  k_scan1<<<gbScan, 256, 0, stream>>>(cnt, rp, bsum);
  k_scan2<<<1, 64, 0, stream>>>(bsum, gbScan);
  k_scan3<<<gbN, 256, 0, stream>>>(rp, bsum);
  k_scatter<<<gbE, 256, 0, stream>>>(ei, rp, slot, dinv, e2);

  k_mask<<<gbMask, 256, 0, stream>>>(m1, m2, kd1a, kd1b, kd2a, kd2b);
  k_wsplit<<<32, 64, 0, stream>>>(W1, 128, w1h, w1l);
  k_wsplit<<<32, 64, 0, stream>>>(W2, 128, w2h, w2l);
  k_wsplit<<<16, 64, 0, stream>>>(W3, 64, w3h, w3l);

  k_gemm1<<<gbGemm, 256, 0, stream>>>(x, w1h, w1l, hb);
  k_agg_mid<<<gbAgg, 256, 0, stream>>>(hb, rp, e2, dinv, b1, m1, ah, al);
  k_gemm_mfma<128><<<gbGemm, 256, 0, stream>>>(ah, al, w2h, w2l, hb);
  k_agg_mid<<<gbAgg, 256, 0, stream>>>(hb, rp, e2, dinv, b2, m2, ah, al);
  k_gemm_mfma<64><<<gbGemm, 256, 0, stream>>>(ah, al, w3h, w3l, hb);
  k_agg_final<<<gbAgg, 256, 0, stream>>>(hb, rp, e2, dinv, b3, out);
}

// Round 8
// 398.316 us; speedup vs baseline: 1.1070x; 1.1070x over previous
//
#include <hip/hip_runtime.h>
#include <stdint.h>

#define NN 100000
#define NE 1600000
#define NMASKW 400000   // (NN*128)/32 mask words per layer
#define GB_E 6250       // hist blocks
#define GB_MASK 1563    // mask blocks

typedef float f4 __attribute__((ext_vector_type(4)));
typedef float f2 __attribute__((ext_vector_type(2)));
typedef unsigned short us4 __attribute__((ext_vector_type(4)));
typedef short s16x8 __attribute__((ext_vector_type(8)));

__device__ inline float bf2f(unsigned short u) {
  return __uint_as_float(((uint32_t)u) << 16);
}
__device__ inline unsigned short f2bf(float f) {  // round-to-nearest-even
  uint32_t u = __float_as_uint(f);
  return (unsigned short)((u + 0x7fffu + ((u >> 16) & 1u)) >> 16);
}
__device__ inline float lo16(uint32_t q) { return __uint_as_float(q << 16); }
__device__ inline float hi16(uint32_t q) { return __uint_as_float(q & 0xffff0000u); }

// Threefry-2x32, 20 rounds (Random123 / JAX exact).
__host__ __device__ inline void threefry2x32(uint32_t k0, uint32_t k1,
                                             uint32_t x0, uint32_t x1,
                                             uint32_t* y0, uint32_t* y1) {
  uint32_t ks[3] = {k0, k1, k0 ^ k1 ^ 0x1BD11BDAu};
  x0 += ks[0]; x1 += ks[1];
  const uint32_t R[2][4] = {{13u, 15u, 26u, 6u}, {17u, 29u, 16u, 24u}};
#pragma unroll
  for (int i = 0; i < 5; ++i) {
#pragma unroll
    for (int j = 0; j < 4; ++j) {
      uint32_t r = R[i & 1][j];
      x0 += x1;
      x1 = (x1 << r) | (x1 >> (32u - r));
      x1 ^= x0;
    }
    x0 += ks[(i + 1) % 3];
    x1 += ks[(i + 2) % 3] + (uint32_t)(i + 1);
  }
  *y0 = x0; *y1 = x1;
}

__device__ inline uint32_t tf_bits32(uint32_t k0, uint32_t k1, uint32_t idx) {
  uint32_t a, b;
  threefry2x32(k0, k1, 0u, idx, &a, &b);
  return a ^ b;
}

// Fused: hist blocks (atomic/memory-bound) interleaved 4:1 with mask blocks
// (pure VALU) so the CU scheduler overlaps them.
__global__ __launch_bounds__(256) void k_histmask(
    const int* __restrict__ ei, uint32_t* __restrict__ cnt,
    int* __restrict__ slot, uint32_t* __restrict__ m1, uint32_t* __restrict__ m2,
    uint32_t k10, uint32_t k11, uint32_t k20, uint32_t k21) {
  int b = blockIdx.x;
  int q = b / 5, r = b % 5;
  if (r < 4) {
    int e = (q * 4 + r) * 256 + threadIdx.x;
    if (e < NE) {
      int d = ei[NE + e];
      slot[e] = (int)atomicAdd(&cnt[d], 1u);
    }
  } else {
    int t = q * 256 + threadIdx.x;
    if (t < NMASKW) {
      uint32_t base = (uint32_t)t * 32u;
      uint32_t w1 = 0, w2 = 0;
#pragma unroll 4
      for (int j = 0; j < 32; ++j) {
        w1 |= (tf_bits32(k10, k11, base + j) >> 31) << j;
        w2 |= (tf_bits32(k20, k21, base + j) >> 31) << j;
      }
      m1[t] = w1;
      m2[t] = w2;
    }
  }
}

// Scan (exclusive, two-level) fused with dinv computation.
__global__ __launch_bounds__(256) void k_scan1(const uint32_t* __restrict__ cnt,
                                               uint32_t* __restrict__ rp,
                                               uint32_t* __restrict__ bsum,
                                               float* __restrict__ dinv) {
  __shared__ uint32_t sh[256];
  int t = threadIdx.x;
  int base = blockIdx.x * 1024 + t * 4;
  uint32_t v[4];
  uint32_t s = 0;
#pragma unroll
  for (int i = 0; i < 4; ++i) {
    int idx = base + i;
    v[i] = (idx < NN) ? cnt[idx] : 0u;
    if (idx < NN) dinv[idx] = 1.0f / sqrtf((float)(v[i] + 1u));
    s += v[i];
  }
  sh[t] = s;
  __syncthreads();
  for (int off = 1; off < 256; off <<= 1) {
    uint32_t x = sh[t];
    if (t >= off) x += sh[t - off];
    __syncthreads();
    sh[t] = x;
    __syncthreads();
  }
  uint32_t run = (t > 0) ? sh[t - 1] : 0u;
  if (t == 255) bsum[blockIdx.x] = sh[255];
#pragma unroll
  for (int i = 0; i < 4; ++i) {
    int idx = base + i;
    if (idx < NN) rp[idx] = run;
    run += v[i];
  }
}

__global__ void k_scan2(uint32_t* bsum, int nb) {
  if (threadIdx.x == 0 && blockIdx.x == 0) {
    uint32_t s = 0;
    for (int i = 0; i < nb; ++i) { uint32_t x = bsum[i]; bsum[i] = s; s += x; }
  }
}

__global__ void k_scan3(uint32_t* rp, const uint32_t* __restrict__ bsum) {
  int i = blockIdx.x * 256 + threadIdx.x;
  if (i < NN) rp[i] += bsum[i >> 10];
  if (i == 0) rp[NN] = (uint32_t)NE;
}

// Edge record (src, w=dinv[s]*dinv[d]) at CSR position; no atomics.
__global__ void k_scatter(const int* __restrict__ ei,
                          const uint32_t* __restrict__ rp,
                          const int* __restrict__ slot,
                          const float* __restrict__ dinv,
                          uint2* __restrict__ e2) {
  int e = blockIdx.x * 256 + threadIdx.x;
  if (e < NE) {
    int s = ei[e];
    int d = ei[NE + e];
    float w = dinv[s] * dinv[d];
    uint32_t pos = rp[d] + (uint32_t)slot[e];
    uint2 rec;
    rec.x = (uint32_t)s;
    rec.y = __float_as_uint(w);
    e2[pos] = rec;
  }
}

// All three W splits in one launch. blocks: [0,32) W1, [32,64) W2, [64,80) W3.
__global__ void k_wsplit3(const float* __restrict__ W1, const float* __restrict__ W2,
                          const float* __restrict__ W3,
                          unsigned short* __restrict__ w1h, unsigned short* __restrict__ w1l,
                          unsigned short* __restrict__ w2h, unsigned short* __restrict__ w2l,
                          unsigned short* __restrict__ w3h, unsigned short* __restrict__ w3l) {
  int b = blockIdx.x;
  const float* W; unsigned short *H, *L; int dout, bb;
  if (b < 32)      { W = W1; H = w1h; L = w1l; dout = 128; bb = b; }
  else if (b < 64) { W = W2; H = w2h; L = w2l; dout = 128; bb = b - 32; }
  else             { W = W3; H = w3h; L = w3l; dout = 64;  bb = b - 64; }
  int lane = threadIdx.x;  // 64
  int kk = bb & 3;
  int ct = bb >> 2;
  int kbase = kk * 32 + (lane >> 4) * 8;
  int col = ct * 16 + (lane & 15);
  us4 h0, h1, l0, l1;
#pragma unroll
  for (int j = 0; j < 4; ++j) {
    float v = W[(size_t)(kbase + j) * dout + col];
    h0[j] = f2bf(v);
    l0[j] = f2bf(v - bf2f(h0[j]));
    float v2 = W[(size_t)(kbase + 4 + j) * dout + col];
    h1[j] = f2bf(v2);
    l1[j] = f2bf(v2 - bf2f(h1[j]));
  }
  size_t o = ((size_t)bb * 64 + lane) * 8;
  *(us4*)(H + o) = h0; *(us4*)(H + o + 4) = h1;
  *(us4*)(L + o) = l0; *(us4*)(L + o + 4) = l1;
}

// Layer-1 GEMM: A is f32 (x), split hi/lo in-register. C bf16.
__global__ __launch_bounds__(256) void k_gemm1(
    const float* __restrict__ A, const unsigned short* __restrict__ Wh,
    const unsigned short* __restrict__ Wl, unsigned short* __restrict__ C) {
  constexpr int NT = 8;  // DOUT=128
  const int w = threadIdx.x >> 6;
  const int lane = threadIdx.x & 63;
  const int row0 = blockIdx.x * 64 + w * 16;
  int ar = row0 + (lane & 15);
  if (ar >= NN) ar = NN - 1;
  const int aoff = (lane >> 4) * 8;
  s16x8 afh[4], afl[4];
#pragma unroll
  for (int kk = 0; kk < 4; ++kk) {
    f4 v0 = *(const f4*)(A + (size_t)ar * 128 + kk * 32 + aoff);
    f4 v1 = *(const f4*)(A + (size_t)ar * 128 + kk * 32 + aoff + 4);
#pragma unroll
    for (int j = 0; j < 4; ++j) {
      unsigned short h = f2bf(v0[j]);
      afh[kk][j] = (short)h;
      afl[kk][j] = (short)f2bf(v0[j] - bf2f(h));
      unsigned short h2 = f2bf(v1[j]);
      afh[kk][j + 4] = (short)h2;
      afl[kk][j + 4] = (short)f2bf(v1[j] - bf2f(h2));
    }
  }
  f4 acc[NT];
#pragma unroll
  for (int t = 0; t < NT; ++t) acc[t] = (f4){0.f, 0.f, 0.f, 0.f};
#pragma unroll
  for (int ct = 0; ct < NT; ++ct) {
#pragma unroll
    for (int kk = 0; kk < 4; ++kk) {
      size_t bo = ((size_t)(ct * 4 + kk) * 64 + lane) * 8;
      s16x8 bh = *(const s16x8*)(Wh + bo);
      s16x8 bl = *(const s16x8*)(Wl + bo);
      acc[ct] = __builtin_amdgcn_mfma_f32_16x16x32_bf16(afh[kk], bh, acc[ct], 0, 0, 0);
      acc[ct] = __builtin_amdgcn_mfma_f32_16x16x32_bf16(afh[kk], bl, acc[ct], 0, 0, 0);
      acc[ct] = __builtin_amdgcn_mfma_f32_16x16x32_bf16(afl[kk], bh, acc[ct], 0, 0, 0);
    }
  }
  const int rbase = row0 + (lane >> 4) * 4;
  const int cbase = lane & 15;
#pragma unroll
  for (int ct = 0; ct < NT; ++ct) {
#pragma unroll
    for (int r = 0; r < 4; ++r) {
      int gr = rbase + r;
      if (gr < NN) C[(size_t)gr * 128 + ct * 16 + cbase] = f2bf(acc[ct][r]);
    }
  }
}

// Layers 2/3 GEMM: A from hi/lo bf16 arrays (agg output).
template <int DOUT>
__global__ __launch_bounds__(256) void k_gemm_mfma(
    const unsigned short* __restrict__ Ah, const unsigned short* __restrict__ Al,
    const unsigned short* __restrict__ Wh, const unsigned short* __restrict__ Wl,
    unsigned short* __restrict__ C) {
  constexpr int NT = DOUT / 16;
  const int w = threadIdx.x >> 6;
  const int lane = threadIdx.x & 63;
  const int row0 = blockIdx.x * 64 + w * 16;
  int ar = row0 + (lane & 15);
  if (ar >= NN) ar = NN - 1;
  const int aoff = (lane >> 4) * 8;
  s16x8 afh[4], afl[4];
#pragma unroll
  for (int kk = 0; kk < 4; ++kk) {
    afh[kk] = *(const s16x8*)(Ah + (size_t)ar * 128 + kk * 32 + aoff);
    afl[kk] = *(const s16x8*)(Al + (size_t)ar * 128 + kk * 32 + aoff);
  }
  f4 acc[NT];
#pragma unroll
  for (int t = 0; t < NT; ++t) acc[t] = (f4){0.f, 0.f, 0.f, 0.f};
#pragma unroll
  for (int ct = 0; ct < NT; ++ct) {
#pragma unroll
    for (int kk = 0; kk < 4; ++kk) {
      size_t bo = ((size_t)(ct * 4 + kk) * 64 + lane) * 8;
      s16x8 bh = *(const s16x8*)(Wh + bo);
      s16x8 bl = *(const s16x8*)(Wl + bo);
      acc[ct] = __builtin_amdgcn_mfma_f32_16x16x32_bf16(afh[kk], bh, acc[ct], 0, 0, 0);
      acc[ct] = __builtin_amdgcn_mfma_f32_16x16x32_bf16(afh[kk], bl, acc[ct], 0, 0, 0);
      acc[ct] = __builtin_amdgcn_mfma_f32_16x16x32_bf16(afl[kk], bh, acc[ct], 0, 0, 0);
    }
  }
  const int rbase = row0 + (lane >> 4) * 4;
  const int cbase = lane & 15;
#pragma unroll
  for (int ct = 0; ct < NT; ++ct) {
#pragma unroll
    for (int r = 0; r < 4; ++r) {
      int gr = rbase + r;
      if (gr < NN) C[(size_t)gr * DOUT + ct * 16 + cbase] = f2bf(acc[ct][r]);
    }
  }
}

// Middle aggregation (D=128): one wave per node; each lane loads 16B so one
// instruction gathers 4 edge rows (quarter q = lane>>4 owns edge slot q,
// features (lane&15)*8..+7). Cross-quarter reduce via shfl_xor(16|32).
__global__ __launch_bounds__(256) void k_agg_mid(
    const unsigned short* __restrict__ hb, const uint32_t* __restrict__ rp,
    const uint2* __restrict__ e2, const float* __restrict__ dinv,
    const float* __restrict__ bias, const uint32_t* __restrict__ mask,
    unsigned short* __restrict__ oh, unsigned short* __restrict__ ol) {
  int wid = __builtin_amdgcn_readfirstlane(blockIdx.x * 4 + (threadIdx.x >> 6));
  if (wid >= NN) return;
  const int lane = threadIdx.x & 63;
  const int q = lane >> 4;    // edge slot in group of 4
  const int fl = lane & 15;   // feature block: 8 features at fl*8
  const uint32_t beg = rp[wid], end = rp[wid + 1];
  const float dv = dinv[wid];
  const float sn = dv * dv;
  const char* hbase = (const char*)hb;
  float acc[8];
#pragma unroll
  for (int j = 0; j < 8; ++j) acc[j] = 0.f;

  uint32_t u = beg;
  for (; u + 8 <= end; u += 8) {
    uint2 r0 = e2[u + q];
    uint2 r1 = e2[u + 4 + q];
    uint4 g0 = *(const uint4*)(hbase + ((size_t)r0.x << 8) + fl * 16);
    uint4 g1 = *(const uint4*)(hbase + ((size_t)r1.x << 8) + fl * 16);
    float w0 = __uint_as_float(r0.y), w1 = __uint_as_float(r1.y);
    acc[0] = fmaf(w0, lo16(g0.x), acc[0]); acc[1] = fmaf(w0, hi16(g0.x), acc[1]);
    acc[2] = fmaf(w0, lo16(g0.y), acc[2]); acc[3] = fmaf(w0, hi16(g0.y), acc[3]);
    acc[4] = fmaf(w0, lo16(g0.z), acc[4]); acc[5] = fmaf(w0, hi16(g0.z), acc[5]);
    acc[6] = fmaf(w0, lo16(g0.w), acc[6]); acc[7] = fmaf(w0, hi16(g0.w), acc[7]);
    acc[0] = fmaf(w1, lo16(g1.x), acc[0]); acc[1] = fmaf(w1, hi16(g1.x), acc[1]);
    acc[2] = fmaf(w1, lo16(g1.y), acc[2]); acc[3] = fmaf(w1, hi16(g1.y), acc[3]);
    acc[4] = fmaf(w1, lo16(g1.z), acc[4]); acc[5] = fmaf(w1, hi16(g1.z), acc[5]);
    acc[6] = fmaf(w1, lo16(g1.w), acc[6]); acc[7] = fmaf(w1, hi16(g1.w), acc[7]);
  }
  for (; u < end; u += 4) {  // tail: 4 slots, weight-zeroed OOB
    uint32_t idx = u + (uint32_t)q;
    uint32_t cidx = idx < end ? idx : end - 1u;
    uint2 r = e2[cidx];
    float w = (idx < end) ? __uint_as_float(r.y) : 0.f;
    uint4 g = *(const uint4*)(hbase + ((size_t)r.x << 8) + fl * 16);
    acc[0] = fmaf(w, lo16(g.x), acc[0]); acc[1] = fmaf(w, hi16(g.x), acc[1]);
    acc[2] = fmaf(w, lo16(g.y), acc[2]); acc[3] = fmaf(w, hi16(g.y), acc[3]);
    acc[4] = fmaf(w, lo16(g.z), acc[4]); acc[5] = fmaf(w, hi16(g.z), acc[5]);
    acc[6] = fmaf(w, lo16(g.w), acc[6]); acc[7] = fmaf(w, hi16(g.w), acc[7]);
  }
#pragma unroll
  for (int j = 0; j < 8; ++j) acc[j] += __shfl_xor(acc[j], 16);
#pragma unroll
  for (int j = 0; j < 8; ++j) acc[j] += __shfl_xor(acc[j], 32);

  // self-loop + bias + relu + dropout
  uint4 qs = *(const uint4*)(hbase + ((size_t)(uint32_t)wid << 8) + fl * 16);
  f4 b0 = *(const f4*)(bias + fl * 8);
  f4 b1 = *(const f4*)(bias + fl * 8 + 4);
  acc[0] = fmaf(sn, lo16(qs.x), acc[0]) + b0[0];
  acc[1] = fmaf(sn, hi16(qs.x), acc[1]) + b0[1];
  acc[2] = fmaf(sn, lo16(qs.y), acc[2]) + b0[2];
  acc[3] = fmaf(sn, hi16(qs.y), acc[3]) + b0[3];
  acc[4] = fmaf(sn, lo16(qs.z), acc[4]) + b1[0];
  acc[5] = fmaf(sn, hi16(qs.z), acc[5]) + b1[1];
  acc[6] = fmaf(sn, lo16(qs.w), acc[6]) + b1[2];
  acc[7] = fmaf(sn, hi16(qs.w), acc[7]) + b1[3];
  uint32_t mw = mask[(uint32_t)wid * 4u + (uint32_t)(fl >> 2)];
  uint32_t bb = (uint32_t)((fl & 3) * 8);
#pragma unroll
  for (int j = 0; j < 8; ++j) {
    float a = fmaxf(acc[j], 0.f);
    acc[j] = ((mw >> (bb + j)) & 1u) ? 0.f : a * 2.f;
  }
  // split hi/lo; quarter 0 writes oh, quarter 1 writes ol (coalesced 16B each)
  uint32_t hw[4], lw[4];
#pragma unroll
  for (int j = 0; j < 4; ++j) {
    unsigned short h0 = f2bf(acc[2 * j]), h1 = f2bf(acc[2 * j + 1]);
    unsigned short g0 = f2bf(acc[2 * j] - bf2f(h0));
    unsigned short g1 = f2bf(acc[2 * j + 1] - bf2f(h1));
    hw[j] = (uint32_t)h0 | ((uint32_t)h1 << 16);
    lw[j] = (uint32_t)g0 | ((uint32_t)g1 << 16);
  }
  if (q == 0) {
    uint4 v = {hw[0], hw[1], hw[2], hw[3]};
    *(uint4*)(oh + (size_t)(uint32_t)wid * 128 + fl * 8) = v;
  } else if (q == 1) {
    uint4 v = {lw[0], lw[1], lw[2], lw[3]};
    *(uint4*)(ol + (size_t)(uint32_t)wid * 128 + fl * 8) = v;
  }
}

// Final aggregation (D=64): 8B per lane -> 4 rows (128B) per instruction.
__global__ __launch_bounds__(256) void k_agg_final(
    const unsigned short* __restrict__ hb, const uint32_t* __restrict__ rp,
    const uint2* __restrict__ e2, const float* __restrict__ dinv,
    const float* __restrict__ bias, float* __restrict__ out) {
  int wid = __builtin_amdgcn_readfirstlane(blockIdx.x * 4 + (threadIdx.x >> 6));
  if (wid >= NN) return;
  const int lane = threadIdx.x & 63;
  const int q = lane >> 4;
  const int fl = lane & 15;  // 4 features at fl*4
  const uint32_t beg = rp[wid], end = rp[wid + 1];
  const float dv = dinv[wid];
  const float sn = dv * dv;
  const char* hbase = (const char*)hb;
  float acc[4];
#pragma unroll
  for (int j = 0; j < 4; ++j) acc[j] = 0.f;

  uint32_t u = beg;
  for (; u + 8 <= end; u += 8) {
    uint2 r0 = e2[u + q];
    uint2 r1 = e2[u + 4 + q];
    uint2 g0 = *(const uint2*)(hbase + ((size_t)r0.x << 7) + fl * 8);
    uint2 g1 = *(const uint2*)(hbase + ((size_t)r1.x << 7) + fl * 8);
    float w0 = __uint_as_float(r0.y), w1 = __uint_as_float(r1.y);
    acc[0] = fmaf(w0, lo16(g0.x), acc[0]); acc[1] = fmaf(w0, hi16(g0.x), acc[1]);
    acc[2] = fmaf(w0, lo16(g0.y), acc[2]); acc[3] = fmaf(w0, hi16(g0.y), acc[3]);
    acc[0] = fmaf(w1, lo16(g1.x), acc[0]); acc[1] = fmaf(w1, hi16(g1.x), acc[1]);
    acc[2] = fmaf(w1, lo16(g1.y), acc[2]); acc[3] = fmaf(w1, hi16(g1.y), acc[3]);
  }
  for (; u < end; u += 4) {
    uint32_t idx = u + (uint32_t)q;
    uint32_t cidx = idx < end ? idx : end - 1u;
    uint2 r = e2[cidx];
    float w = (idx < end) ? __uint_as_float(r.y) : 0.f;
    uint2 g = *(const uint2*)(hbase + ((size_t)r.x << 7) + fl * 8);
    acc[0] = fmaf(w, lo16(g.x), acc[0]); acc[1] = fmaf(w, hi16(g.x), acc[1]);
    acc[2] = fmaf(w, lo16(g.y), acc[2]); acc[3] = fmaf(w, hi16(g.y), acc[3]);
  }
#pragma unroll
  for (int j = 0; j < 4; ++j) acc[j] += __shfl_xor(acc[j], 16);
#pragma unroll
  for (int j = 0; j < 4; ++j) acc[j] += __shfl_xor(acc[j], 32);

  uint2 qs = *(const uint2*)(hbase + ((size_t)(uint32_t)wid << 7) + fl * 8);
  f4 bv = *(const f4*)(bias + fl * 4);
  acc[0] = fmaf(sn, lo16(qs.x), acc[0]) + bv[0];
  acc[1] = fmaf(sn, hi16(qs.x), acc[1]) + bv[1];
  acc[2] = fmaf(sn, lo16(qs.y), acc[2]) + bv[2];
  acc[3] = fmaf(sn, hi16(qs.y), acc[3]) + bv[3];
  if (q == 0) {
    f4 v = {acc[0], acc[1], acc[2], acc[3]};
    *(f4*)(out + (size_t)(uint32_t)wid * 64 + fl * 4) = v;
  }
}

extern "C" void kernel_launch(void* const* d_in, const int* in_sizes, int n_in,
                              void* d_out, int out_size, void* d_ws, size_t ws_size,
                              hipStream_t stream) {
  (void)in_sizes; (void)n_in; (void)out_size; (void)ws_size;
  const float* x  = (const float*)d_in[0];
  const float* W1 = (const float*)d_in[1];
  const float* b1 = (const float*)d_in[2];
  const float* W2 = (const float*)d_in[3];
  const float* b2 = (const float*)d_in[4];
  const float* W3 = (const float*)d_in[5];
  const float* b3 = (const float*)d_in[6];
  const int* ei   = (const int*)d_in[7];
  float* out = (float*)d_out;

  char* p = (char*)d_ws;
  auto alloc = [&](size_t bytes) -> void* {
    void* r = (void*)p;
    p += (bytes + 255) & ~(size_t)255;
    return r;
  };
  uint32_t* cnt  = (uint32_t*)alloc((size_t)NN * 4);
  float*    dinv = (float*)alloc((size_t)NN * 4);
  uint32_t* rp   = (uint32_t*)alloc((size_t)(NN + 1) * 4);
  uint32_t* bsum = (uint32_t*)alloc(1024);
  int*      slot = (int*)alloc((size_t)NE * 4);
  uint2*    e2   = (uint2*)alloc((size_t)NE * 8);
  uint32_t* m1   = (uint32_t*)alloc((size_t)NMASKW * 4);
  uint32_t* m2   = (uint32_t*)alloc((size_t)NMASKW * 4);
  unsigned short* ah = (unsigned short*)alloc((size_t)NN * 128 * 2);
  unsigned short* al = (unsigned short*)alloc((size_t)NN * 128 * 2);
  unsigned short* hb = (unsigned short*)alloc((size_t)NN * 128 * 2);
  unsigned short* w1h = (unsigned short*)alloc(32 * 64 * 8 * 2);
  unsigned short* w1l = (unsigned short*)alloc(32 * 64 * 8 * 2);
  unsigned short* w2h = (unsigned short*)alloc(32 * 64 * 8 * 2);
  unsigned short* w2l = (unsigned short*)alloc(32 * 64 * 8 * 2);
  unsigned short* w3h = (unsigned short*)alloc(16 * 64 * 8 * 2);
  unsigned short* w3l = (unsigned short*)alloc(16 * 64 * 8 * 2);

  // JAX: kd1, kd2 = split(key(42)) — partitionable/fold-like split.
  uint32_t kd1a, kd1b, kd2a, kd2b;
  threefry2x32(0u, 42u, 0u, 0u, &kd1a, &kd1b);
  threefry2x32(0u, 42u, 0u, 1u, &kd2a, &kd2b);

  const int gbN = (NN + 255) / 256;
  const int gbE = (NE + 255) / 256;
  const int gbScan = (NN + 1023) / 1024;
  const int gbGemm = (NN + 63) / 64;
  const int gbAgg = (NN + 3) / 4;

  hipMemsetAsync(cnt, 0, (size_t)NN * 4, stream);
  k_histmask<<<8000, 256, 0, stream>>>(ei, cnt, slot, m1, m2, kd1a, kd1b, kd2a, kd2b);
  k_scan1<<<gbScan, 256, 0, stream>>>(cnt, rp, bsum, dinv);
  k_scan2<<<1, 64, 0, stream>>>(bsum, gbScan);
  k_scan3<<<gbN, 256, 0, stream>>>(rp, bsum);
  k_scatter<<<gbE, 256, 0, stream>>>(ei, rp, slot, dinv, e2);
  k_wsplit3<<<80, 64, 0, stream>>>(W1, W2, W3, w1h, w1l, w2h, w2l, w3h, w3l);

  k_gemm1<<<gbGemm, 256, 0, stream>>>(x, w1h, w1l, hb);
  k_agg_mid<<<gbAgg, 256, 0, stream>>>(hb, rp, e2, dinv, b1, m1, ah, al);
  k_gemm_mfma<128><<<gbGemm, 256, 0, stream>>>(ah, al, w2h, w2l, hb);
  k_agg_mid<<<gbAgg, 256, 0, stream>>>(hb, rp, e2, dinv, b2, m2, ah, al);
  k_gemm_mfma<64><<<gbGemm, 256, 0, stream>>>(ah, al, w3h, w3l, hb);
  k_agg_final<<<gbAgg, 256, 0, stream>>>(hb, rp, e2, dinv, b3, out);
}